// Round 1
// baseline (362.844 us; speedup 1.0000x reference)
//
#include <hip/hip_runtime.h>
#include <math.h>

#define N_TOT 4096   // H*P*D
#define PHO_T 4096   // P*H*OUT_DIM
#define KTOT  40960  // 2*N + 8*N

// ---------------------------------------------------------------------------
// Pass 1: activation matrix A[k][b], k-major, b minor (32 floats per k row).
//   k in [0,4096)      : silu(q[b][n]),  n = k
//   k in [4096,8192)   : silu(k[b][n])
//   k in [8192,40960)  : sin(grid_f*q)*ce_q + sin(grid_f*k)*ce_k, f-major
// ---------------------------------------------------------------------------
__global__ void act_kernel(const float* __restrict__ q,
                           const float* __restrict__ kx,
                           const float* __restrict__ grid_,
                           const float* __restrict__ coefq,
                           const float* __restrict__ coefk,
                           float* __restrict__ A)
{
    const int t = blockIdx.x * 256 + threadIdx.x;  // 131072 total = 4096 n * 32 b
    const int b = t & 31;
    const int n = t >> 5;
    const float qv = q[(size_t)b * N_TOT + n];
    const float kv = kx[(size_t)b * N_TOT + n];
    A[(size_t)n * 32 + b]           = qv / (1.f + __expf(-qv));
    A[(size_t)(N_TOT + n) * 32 + b] = kv / (1.f + __expf(-kv));
    const int g = n >> 6;  // group = n/64
#pragma unroll
    for (int f = 0; f < 8; ++f) {
        const float gf = grid_[f];
        const float s = sinf(gf * qv) * coefq[g * 8 + f]
                      + sinf(gf * kv) * coefk[g * 8 + f];
        A[(size_t)(2 * N_TOT + f * N_TOT + n) * 32 + b] = s;
    }
}

// ---------------------------------------------------------------------------
// y_pre[b][o] initialized with the bias term: 2 * ss[o]^2 * sum_f conv_bq[f][o]
// ---------------------------------------------------------------------------
__global__ void init_kernel(const float* __restrict__ cb,
                            const float* __restrict__ ssp,
                            float* __restrict__ ypre)
{
    const int t = blockIdx.x * 256 + threadIdx.x;  // t = b*4096 + o
    const int o = t & 4095;
    const float s = ssp[o];
    float acc = 0.f;
#pragma unroll
    for (int f = 0; f < 8; ++f) acc += cb[f * PHO_T + o];
    ypre[t] = 2.f * s * s * acc;
}

// ---------------------------------------------------------------------------
// Main GEMM: y_pre[b][o] += scale * sum_k A[k][b] * W[k][o]
// Grid: 160 K-supers (256 k each, region-aligned) x 16 o-blocks (256 o each).
// Block: 128 threads; each thread owns 2 o's and all 32 b's (64 f32 acc).
// W staged global->LDS [o][k] (stride 10, double-buffered). A read with
// wave-uniform addresses (compiler scalarizes to s_load -> SGPR broadcast).
// ---------------------------------------------------------------------------
#define OBK  256
#define KC   8
#define WST  10
#define KSUP 256
#define NCH  (KSUP / KC)   // 32 chunks per block

__global__ __launch_bounds__(128) void gemm_kernel(
    const float* __restrict__ bwq, const float* __restrict__ bwk,
    const float* __restrict__ cw,  const float* __restrict__ A,
    const float* __restrict__ ssp, float* __restrict__ ypre)
{
    __shared__ float Wl[2][OBK * WST];   // 2*256*10*4 = 20480 B

    const int t  = threadIdx.x;
    const int ks = blockIdx.x >> 4;      // 0..159
    const int ob = blockIdx.x & 15;      // 0..15
    const int o_base = ob * OBK;

    const float* Wp;
    int a_koff;
    bool scaled;
    if (ks < 16) {                       // base_weight_q
        Wp = bwq + ks * 256;
        a_koff = ks * 256;
        scaled = false;
    } else if (ks < 32) {                // base_weight_k
        Wp = bwk + (ks - 16) * 256;
        a_koff = 4096 + (ks - 16) * 256;
        scaled = false;
    } else {                             // conv_wq, scaled by ss^2
        const int c2 = ks - 32;          // 0..127
        const int f  = c2 >> 4;          // 0..7
        const int noff = (c2 & 15) * 256;
        Wp = cw + (size_t)f * (size_t)PHO_T * N_TOT + noff;
        a_koff = 8192 + f * 4096 + noff;
        scaled = true;
    }

    const int o_l  = t >> 1;  // 0..63
    const int quad = t & 1;   // which float4 of the 8-k chunk

    float acc0[32], acc1[32];
#pragma unroll
    for (int i = 0; i < 32; ++i) { acc0[i] = 0.f; acc1[i] = 0.f; }

    float4 wreg[4];

    // prologue: stage chunk 0
#pragma unroll
    for (int j = 0; j < 4; ++j) {
        const int row = o_l + j * 64;
        wreg[j] = *(const float4*)(Wp + (size_t)(o_base + row) * N_TOT + quad * 4);
    }
#pragma unroll
    for (int j = 0; j < 4; ++j) {
        const int row = o_l + j * 64;
        float* p = &Wl[0][row * WST + quad * 4];
        ((float2*)p)[0] = make_float2(wreg[j].x, wreg[j].y);
        ((float2*)p)[1] = make_float2(wreg[j].z, wreg[j].w);
    }
    __syncthreads();

    for (int c = 0; c < NCH; ++c) {
        const int cur = c & 1;
        if (c + 1 < NCH) {   // issue next chunk's global loads (in flight over compute)
            const int kl = (c + 1) * KC;
#pragma unroll
            for (int j = 0; j < 4; ++j) {
                const int row = o_l + j * 64;
                wreg[j] = *(const float4*)(Wp + (size_t)(o_base + row) * N_TOT + kl + quad * 4);
            }
        }
        // compute chunk c from LDS buffer `cur`
        const float* __restrict__ w0 = &Wl[cur][t * WST];
        const float* __restrict__ w1 = &Wl[cur][(t + 128) * WST];
        const float* __restrict__ Ab = A + ((size_t)a_koff + (size_t)c * KC) * 32;
#pragma unroll
        for (int kk = 0; kk < KC; ++kk) {
            const float wv0 = w0[kk];
            const float wv1 = w1[kk];
            const float4* __restrict__ ap = (const float4*)(Ab + kk * 32);
#pragma unroll
            for (int j4 = 0; j4 < 8; ++j4) {
                const float4 a = ap[j4];   // wave-uniform -> SGPR broadcast
                acc0[j4*4+0] = fmaf(a.x, wv0, acc0[j4*4+0]);
                acc0[j4*4+1] = fmaf(a.y, wv0, acc0[j4*4+1]);
                acc0[j4*4+2] = fmaf(a.z, wv0, acc0[j4*4+2]);
                acc0[j4*4+3] = fmaf(a.w, wv0, acc0[j4*4+3]);
                acc1[j4*4+0] = fmaf(a.x, wv1, acc1[j4*4+0]);
                acc1[j4*4+1] = fmaf(a.y, wv1, acc1[j4*4+1]);
                acc1[j4*4+2] = fmaf(a.z, wv1, acc1[j4*4+2]);
                acc1[j4*4+3] = fmaf(a.w, wv1, acc1[j4*4+3]);
            }
        }
        if (c + 1 < NCH) {
            const int nb = cur ^ 1;   // safe: last readers of nb finished before the
                                      // barrier at the end of iteration c-1
#pragma unroll
            for (int j = 0; j < 4; ++j) {
                const int row = o_l + j * 64;
                float* p = &Wl[nb][row * WST + quad * 4];
                ((float2*)p)[0] = make_float2(wreg[j].x, wreg[j].y);
                ((float2*)p)[1] = make_float2(wreg[j].z, wreg[j].w);
            }
            __syncthreads();
        }
    }

    // epilogue: scale (conv blocks get ss^2) and accumulate partials
    const int o0 = o_base + t;
    const int o1 = o_base + 128 + t;
    float s0 = 1.f, s1 = 1.f;
    if (scaled) {
        const float x0 = ssp[o0], x1 = ssp[o1];
        s0 = x0 * x0; s1 = x1 * x1;
    }
#pragma unroll
    for (int b = 0; b < 32; ++b) {
        atomicAdd(&ypre[(size_t)b * PHO_T + o0], acc0[b] * s0);
        atomicAdd(&ypre[(size_t)b * PHO_T + o1], acc1[b] * s1);
    }
}

// ---------------------------------------------------------------------------
// Softmax over the last dim (32) of y.reshape(32,8,16,32): rows of 32
// contiguous elements. One 32-lane group per row.
// ---------------------------------------------------------------------------
__global__ void softmax_kernel(const float* __restrict__ yp,
                               float* __restrict__ out)
{
    const int t  = threadIdx.x;
    const int r  = blockIdx.x * 8 + (t >> 5);  // 4096 rows
    const int od = t & 31;
    const float v = yp[(size_t)r * 32 + od];
    float m = v;
#pragma unroll
    for (int s = 16; s > 0; s >>= 1) m = fmaxf(m, __shfl_xor(m, s, 32));
    const float e = __expf(v - m);
    float sum = e;
#pragma unroll
    for (int s = 16; s > 0; s >>= 1) sum += __shfl_xor(sum, s, 32);
    out[(size_t)r * 32 + od] = e / sum;
}

// ---------------------------------------------------------------------------
extern "C" void kernel_launch(void* const* d_in, const int* in_sizes, int n_in,
                              void* d_out, int out_size, void* d_ws, size_t ws_size,
                              hipStream_t stream)
{
    const float* q    = (const float*)d_in[0];
    const float* k    = (const float*)d_in[1];
    const float* grid = (const float*)d_in[2];
    const float* bwq  = (const float*)d_in[3];
    const float* bwk  = (const float*)d_in[4];
    const float* cq   = (const float*)d_in[5];
    const float* ck   = (const float*)d_in[6];
    const float* cw   = (const float*)d_in[7];
    const float* cb   = (const float*)d_in[8];
    const float* ssp  = (const float*)d_in[9];
    float* out = (float*)d_out;

    float* A    = (float*)d_ws;                                  // 40960*32*4 = 5242880 B
    float* ypre = (float*)((char*)d_ws + (size_t)KTOT * 32 * 4); // 131072*4   =  524288 B

    act_kernel<<<512, 256, 0, stream>>>(q, k, grid, cq, ck, A);
    init_kernel<<<512, 256, 0, stream>>>(cb, ssp, ypre);
    gemm_kernel<<<2560, 128, 0, stream>>>(bwq, bwk, cw, A, ssp, ypre);
    softmax_kernel<<<512, 256, 0, stream>>>(ypre, out);
}